// Round 8
// baseline (39962.308 us; speedup 1.0000x reference)
//
#include <hip/hip_runtime.h>
#include <hip/hip_fp16.h>
#include <stdint.h>

#define SEQ_LEN 16384
#define H       512
#define NWG     32      // WG k owns h[16k..16k+16)
#define HK      16
#define T       512
#define NR      48      // rows per matrix per WG (3 gates x 16)
#define WPITCH  257     // uint32 pitch per weight row (256 data + 1 pad)

typedef unsigned long long u64;

#define LD_AG(p)   __hip_atomic_load((p),      __ATOMIC_RELAXED, __HIP_MEMORY_SCOPE_AGENT)
#define ST_AG(p,v) __hip_atomic_store((p),(v), __ATOMIC_RELAXED, __HIP_MEMORY_SCOPE_AGENT)

// exchange word: [f16 value (hi 16) | step tag (lo 16)]
__global__ void gru_init(uint32_t* __restrict__ tag32) {
    int i = blockIdx.x * blockDim.x + threadIdx.x;
    if (i < H)            ST_AG(&tag32[i], 0u);        // h0 = 0, tag 0
    else if (i < 2 * H)   ST_AG(&tag32[i], 0xFFFFu);   // invalid tag
}

__launch_bounds__(T, 1)
__global__ void gru_main(const float* __restrict__ x,
                         const float* __restrict__ Wih,
                         const float* __restrict__ Whh,
                         const float* __restrict__ bih,
                         const float* __restrict__ bhh,
                         float* __restrict__ out,
                         uint32_t* __restrict__ tag32)
{
    const int wg  = blockIdx.x;
    const int tid = threadIdx.x;
    const int j0  = wg * HK;

    __shared__ uint32_t w_lds[2 * NR * WPITCH];  // rows 0..47 W_ih, 48..95 W_hh (f16 pairs)
    __shared__ float    x_lds[2][H];
    __shared__ float    h_lds[2][H];
    __shared__ float    sums_g[2][NR];
    __shared__ float    bsum_g[NR];
    __shared__ float    bsum_h[NR];

    __half* wh = (__half*)w_lds;

    // ---- prologue: stage weights f32 -> f16 LDS ----
    for (int idx = tid; idx < 2 * NR * H; idx += T) {
        int r  = idx >> 9;                       // 0..95
        int k  = idx & (H - 1);
        int rr = (r < NR) ? r : r - NR;
        int g  = rr >> 4;
        int jj = rr & 15;
        int grow = g * H + j0 + jj;
        float w = (r < NR) ? Wih[(size_t)grow * H + k] : Whh[(size_t)grow * H + k];
        wh[r * (2 * WPITCH) + k] = __float2half(w);
    }
    if (tid < NR) {
        int g  = tid >> 4;
        int jj = tid & 15;
        int grow = g * H + j0 + jj;
        bsum_g[tid] = (g == 2) ? bih[grow] : (bih[grow] + bhh[grow]);
        bsum_h[tid] = (g == 2) ? bhh[grow] : 0.0f;
    }
    if (tid < 128)                               // prefill x_0
        ((float4*)x_lds[0])[tid] = ((const float4*)x)[tid];
    __syncthreads();

    // ---- hh weights into registers (tid 128..383): rows lj,16+lj,32+lj x chunk c16 ----
    const int lj  = ((tid - 128) >> 4) & 15;     // 0..15
    const int c16 = (tid - 128) & 15;            // 0..15
    uint32_t wR[16], wZ[16], wN[16];
    if (tid >= 128 && tid < 384) {
        const uint32_t* rR = w_lds + (NR + lj)      * WPITCH + c16 * 16;
        const uint32_t* rZ = w_lds + (NR + 16 + lj) * WPITCH + c16 * 16;
        const uint32_t* rN = w_lds + (NR + 32 + lj) * WPITCH + c16 * 16;
        #pragma unroll
        for (int i = 0; i < 16; ++i) {
            int s = (i + c16) & 15;
            wR[i] = rR[s]; wZ[i] = rZ[s]; wN[i] = rN[s];
        }
    }
    const float bhR = bsum_h[lj], bhZ = bsum_h[16 + lj], bhN = bsum_h[32 + lj];

    // gi mapping (tid 128..511): 48 rows x 8 chunks
    const int gi_row = (tid - 128) >> 3;         // 0..47
    const int gi_c8  = tid & 7;

    float4 xp;
    if (tid < 128) xp = ((const float4*)(x + H))[tid];   // x_1
    float hprev = 0.0f;                          // own h, replicated across 16-group

    for (int t = 0; t < SEQ_LEN; ++t) {
        const int par = t & 1, nxt = par ^ 1;

        if (tid < 128) {
            // issue x_{t+2} prefetch (hidden under the spin)
            int tq = t + 2; if (tq >= SEQ_LEN) tq = SEQ_LEN - 1;
            float4 xq = ((const float4*)(x + (size_t)tq * H))[tid];

            // ---- R4-proven tight agent-scope spin on 4 words (2x u64) ----
            const uint32_t need = (uint32_t)t & 0xFFFFu;
            const u64 want = (u64)need * 0x0000000100000001ull;
            const u64 M    = 0x0000FFFF0000FFFFull;
            u64* base = (u64*)(tag32 + (size_t)par * H) + 2 * tid;
            u64 va, vb;
            do { va = LD_AG(base);     } while ((va & M) != want);
            do { vb = LD_AG(base + 1); } while ((vb & M) != want);
            int e = 4 * tid;
            h_lds[par][e]     = __half2float(__ushort_as_half((unsigned short)(va >> 16)));
            h_lds[par][e + 1] = __half2float(__ushort_as_half((unsigned short)(va >> 48)));
            h_lds[par][e + 2] = __half2float(__ushort_as_half((unsigned short)(vb >> 16)));
            h_lds[par][e + 3] = __half2float(__ushort_as_half((unsigned short)(vb >> 48)));
            ((float4*)x_lds[nxt])[tid] = xp;     // commit x_{t+1} BEFORE the barrier
            xp = xq;
        } else {
            // ---- gi dots over x_lds[par] (384 threads, weights from LDS) ----
            const uint32_t* gw = w_lds + gi_row * WPITCH + gi_c8 * 32;
            const float2*   B  = (const float2*)(x_lds[par] + gi_c8 * 64);
            float acc = 0.0f;
            #pragma unroll
            for (int i = 0; i < 32; ++i) {
                int s = (i + 4 * gi_c8) & 31;
                uint32_t wp = gw[s];
                float2 wf = __half22float2(*(__half2*)&wp);
                float2 b  = B[s];
                acc = fmaf(wf.x, b.x, fmaf(wf.y, b.y, acc));
            }
            acc += __shfl_xor(acc, 1);
            acc += __shfl_xor(acc, 2);
            acc += __shfl_xor(acc, 4);
            if (gi_c8 == 0) sums_g[par][gi_row] = acc + bsum_g[gi_row];
        }
        __syncthreads();   // A: the ONLY barrier per step

        if (tid >= 128 && tid < 384) {
            // ---- hh dots: 3 rows/thread from registers over h_lds[par] ----
            const float2* B = (const float2*)(h_lds[par]) + c16 * 16;
            float aR = 0.0f, aZ = 0.0f, aN = 0.0f;
            #pragma unroll
            for (int i = 0; i < 16; ++i) {
                int s = (i + c16) & 15;
                float2 b = B[s];
                float2 fR = __half22float2(*(__half2*)&wR[i]);
                float2 fZ = __half22float2(*(__half2*)&wZ[i]);
                float2 fN = __half22float2(*(__half2*)&wN[i]);
                aR = fmaf(fR.x, b.x, fmaf(fR.y, b.y, aR));
                aZ = fmaf(fZ.x, b.x, fmaf(fZ.y, b.y, aZ));
                aN = fmaf(fN.x, b.x, fmaf(fN.y, b.y, aN));
            }
            #pragma unroll
            for (int m = 1; m < 16; m <<= 1) {
                aR += __shfl_xor(aR, m);
                aZ += __shfl_xor(aZ, m);
                aN += __shfl_xor(aN, m);
            }
            // ---- gates: ALL 16 lanes of the group compute identically (no divergence) ----
            float sg0 = sums_g[par][lj];
            float sg1 = sums_g[par][16 + lj];
            float sg2 = sums_g[par][32 + lj];
            float r_ = 1.0f / (1.0f + __expf(-(sg0 + aR + bhR)));
            float z_ = 1.0f / (1.0f + __expf(-(sg1 + aZ + bhZ)));
            float a  = sg2 + r_ * (aN + bhN);
            a = fminf(12.0f, fmaxf(-12.0f, a));
            float e2 = __expf(2.0f * a);
            float n_ = (e2 - 1.0f) / (e2 + 1.0f);
            float hnew = (1.0f - z_) * n_ + z_ * hprev;
            hprev = hnew;
            uint32_t pk = ((uint32_t)__half_as_ushort(__float2half(hnew)) << 16)
                        | ((uint32_t)(t + 1) & 0xFFFFu);
            // pack 2 neighbors' words into one u64 store (lanes 0 and 32 of each wave)
            int lane = (tid - 128) & 63;
            uint32_t hi = __shfl(pk, (lane + 16) & 63);
            if (c16 == 0) {
                if ((lane & 31) == 0) {
                    u64* pb = (u64*)(tag32 + (size_t)nxt * H + j0) + (lj >> 1);
                    ST_AG(pb, ((u64)hi << 32) | (u64)pk);
                }
                out[(size_t)t * H + j0 + lj] = hnew;   // off critical path
            }
        }
        // no second barrier: all cross-phase LDS reuse is parity-separated or
        // ordered by next step's barrier A (audited pairwise).
    }
}

extern "C" void kernel_launch(void* const* d_in, const int* in_sizes, int n_in,
                              void* d_out, int out_size, void* d_ws, size_t ws_size,
                              hipStream_t stream) {
    const float* x   = (const float*)d_in[0];
    const float* Wih = (const float*)d_in[1];
    const float* Whh = (const float*)d_in[2];
    const float* bih = (const float*)d_in[3];
    const float* bhh = (const float*)d_in[4];
    float* out = (float*)d_out;
    uint32_t* tag32 = (uint32_t*)d_ws;           // 4 KB exchange

    gru_init<<<2, 512, 0, stream>>>(tag32);
    gru_main<<<NWG, T, 0, stream>>>(x, Wih, Whh, bih, bhh, out, tag32);
}